// Round 1
// baseline (204.368 us; speedup 1.0000x reference)
//
#include <hip/hip_runtime.h>
#include <math.h>

// Problem constants (GeoFormer.generate_proposal, ScanNet config)
#define BB 4
#define QQ 128
#define NN 50000
#define CC 20
#define ROWS (BB * QQ)          // 512
#define NV4 (NN / 4)            // 12500 float4 per row
#define TPB 256
#define BPR 4                   // blocks per row (grid.x)
#define QUOTA (NV4 / BPR)       // 3125 f32x4 per block
#define FULL_ITERS 12           // 3125 = 12*256 + 53
#define TAIL 53
#define THRESH_CNT 50
#define MIN_CLS 4

// Native clang vector types — required for __builtin_nontemporal_store
typedef float f32x4 __attribute__((ext_vector_type(4)));
typedef int   i32x4 __attribute__((ext_vector_type(4)));

// Workspace (re-initialized by k0 every call; harness poisons ws with 0xAA)
struct Ws {
    float sum[ROWS];
    int   cnt[ROWS];
    int   cls[ROWS];
    int   valid[ROWS];
};

// K0: per-(b,q) argmax over C=20 class logits (jnp.argmax tie-break = first
// max, i.e. strict '>' forward scan), and zero the accumulators.
__global__ void k0_argmax_zero(const float* __restrict__ cls_logits, Ws* ws) {
    int r = blockIdx.x * blockDim.x + threadIdx.x;
    if (r >= ROWS) return;
    const float* p = cls_logits + r * CC;
    float best = p[0];
    int bi = 0;
    #pragma unroll
    for (int c = 1; c < CC; ++c) {
        float v = p[c];
        if (v > best) { best = v; bi = c; }
    }
    ws->cls[r] = bi;
    ws->sum[r] = 0.0f;
    ws->cnt[r] = 0;
}

// K1: main pass. grid = (BPR=4, ROWS). Each block owns 3125 f32x4 of one row:
// 3 batches of 4 unrolled f32x4 iterations per thread, 2-stage software
// pipeline (prefetch next batch's 8 loads before computing current batch),
// then a 53-lane predicated tail. Branchless compute, NT stores.
__global__ __launch_bounds__(256) void k1_select(
        const float* __restrict__ mask_logits,
        const int*   __restrict__ seg_pred,
        float* __restrict__ out_mask,
        Ws* __restrict__ ws) {
    const int row = blockIdx.y;          // 0..511  (b*Q + q)
    const int b   = row >> 7;            // row / Q
    const int cls = ws->cls[row];
    const int off = blockIdx.x * QUOTA;

    const f32x4* __restrict__ ml = (const f32x4*)(mask_logits + (size_t)row * NN) + off;
    const i32x4* __restrict__ sp = (const i32x4*)(seg_pred + b * NN) + off;
    f32x4* __restrict__ om = (f32x4*)(out_mask + (size_t)row * NN) + off;

    const int t = threadIdx.x;

    float lsum = 0.0f;
    int   lcnt = 0;

    // ---- pipelined full batches: 3 batches x 4 iterations x f32x4 ----
    f32x4 v0[4]; i32x4 s0v[4];
    #pragma unroll
    for (int j = 0; j < 4; ++j) {
        v0[j]  = ml[t + j * TPB];
        s0v[j] = sp[t + j * TPB];
    }

    #pragma unroll
    for (int bat = 0; bat < 3; ++bat) {
        f32x4 nv[4]; i32x4 ns[4];
        if (bat < 2) {                   // compile-time resolved (unrolled)
            const int nbase = (bat + 1) * (4 * TPB) + t;
            #pragma unroll
            for (int j = 0; j < 4; ++j) {
                nv[j] = ml[nbase + j * TPB];
                ns[j] = sp[nbase + j * TPB];
            }
        }
        const int base = bat * (4 * TPB) + t;
        #pragma unroll
        for (int j = 0; j < 4; ++j) {
            f32x4 vv = v0[j];
            i32x4 ss = s0v[j];
            // sigmoid(x) > 0.5  <=>  x > 0 ; branchless select + accumulate
            bool c0 = (vv.x > 0.0f) & (ss.x == cls);
            bool c1 = (vv.y > 0.0f) & (ss.y == cls);
            bool c2 = (vv.z > 0.0f) & (ss.z == cls);
            bool c3 = (vv.w > 0.0f) & (ss.w == cls);
            float g0 = 1.0f / (1.0f + __expf(-vv.x));
            float g1 = 1.0f / (1.0f + __expf(-vv.y));
            float g2 = 1.0f / (1.0f + __expf(-vv.z));
            float g3 = 1.0f / (1.0f + __expf(-vv.w));
            f32x4 o;
            o.x = c0 ? 1.0f : 0.0f;
            o.y = c1 ? 1.0f : 0.0f;
            o.z = c2 ? 1.0f : 0.0f;
            o.w = c3 ? 1.0f : 0.0f;
            lsum += (c0 ? g0 : 0.0f) + (c1 ? g1 : 0.0f)
                  + (c2 ? g2 : 0.0f) + (c3 ? g3 : 0.0f);
            lcnt += (int)c0 + (int)c1 + (int)c2 + (int)c3;
            __builtin_nontemporal_store(o, &om[base + j * TPB]);
        }
        #pragma unroll
        for (int j = 0; j < 4; ++j) { v0[j] = nv[j]; s0v[j] = ns[j]; }
    }

    // ---- 53-lane tail (indices 3072..3124 of this block's quota) ----
    if (t < TAIL) {
        const int idx = FULL_ITERS * TPB + t;
        f32x4 vv = ml[idx];
        i32x4 ss = sp[idx];
        bool c0 = (vv.x > 0.0f) & (ss.x == cls);
        bool c1 = (vv.y > 0.0f) & (ss.y == cls);
        bool c2 = (vv.z > 0.0f) & (ss.z == cls);
        bool c3 = (vv.w > 0.0f) & (ss.w == cls);
        float g0 = 1.0f / (1.0f + __expf(-vv.x));
        float g1 = 1.0f / (1.0f + __expf(-vv.y));
        float g2 = 1.0f / (1.0f + __expf(-vv.z));
        float g3 = 1.0f / (1.0f + __expf(-vv.w));
        f32x4 o;
        o.x = c0 ? 1.0f : 0.0f;
        o.y = c1 ? 1.0f : 0.0f;
        o.z = c2 ? 1.0f : 0.0f;
        o.w = c3 ? 1.0f : 0.0f;
        lsum += (c0 ? g0 : 0.0f) + (c1 ? g1 : 0.0f)
              + (c2 ? g2 : 0.0f) + (c3 ? g3 : 0.0f);
        lcnt += (int)c0 + (int)c1 + (int)c2 + (int)c3;
        __builtin_nontemporal_store(o, &om[idx]);
    }

    // ---- wave64 shuffle reduce + one atomic pair per block ----
    #pragma unroll
    for (int offr = 32; offr > 0; offr >>= 1) {
        lsum += __shfl_down(lsum, offr);
        lcnt += __shfl_down(lcnt, offr);
    }
    __shared__ float ssum[4];
    __shared__ int   scnt[4];
    const int wave = threadIdx.x >> 6;
    const int lane = threadIdx.x & 63;
    if (lane == 0) { ssum[wave] = lsum; scnt[wave] = lcnt; }
    __syncthreads();
    if (threadIdx.x == 0) {
        float ts = ssum[0] + ssum[1] + ssum[2] + ssum[3];
        int   tc = scnt[0] + scnt[1] + scnt[2] + scnt[3];
        atomicAdd(&ws->sum[row], ts);
        atomicAdd(&ws->cnt[row], tc);
    }
}

// K2: finalize per-row outputs (scores, valid, cls_pred) + global_ids copy.
__global__ void k2_finalize_gids(const int* __restrict__ fg,
                                 float* __restrict__ out,
                                 Ws* __restrict__ ws) {
    const int idx = blockIdx.x * blockDim.x + threadIdx.x;
    if (idx < ROWS) {
        int   cnt = ws->cnt[idx];
        int   cls = ws->cls[idx];
        float sum = ws->sum[idx];
        int valid = (cnt >= THRESH_CNT) && (cls >= MIN_CLS);
        ws->valid[idx] = valid;
        float* tail = out + (size_t)ROWS * NN;
        tail[idx]            = valid ? (sum / (float)max(cnt, 1)) : 0.0f;  // scores
        tail[ROWS + idx]     = valid ? 1.0f : 0.0f;                        // valid
        tail[2 * ROWS + idx] = (float)cls;                                 // cls_pred
    }
    const int nv4 = (BB * NN) / 4;   // 50000
    if (idx < nv4) {
        float* gids = out + (size_t)ROWS * NN + 3 * ROWS;
        i32x4 v = ((const i32x4*)fg)[idx];
        f32x4 o;
        o.x = (float)v.x; o.y = (float)v.y; o.z = (float)v.z; o.w = (float)v.w;
        __builtin_nontemporal_store(o, &((f32x4*)gids)[idx]);
    }
}

// K3: zero the mask rows where !valid (expected ~20% of rows).
// grid = (BPR=4, ROWS); valid blocks exit after one uniform scalar load.
__global__ __launch_bounds__(256) void k3_fixup(
        float* __restrict__ out_mask, const Ws* __restrict__ ws) {
    const int row = blockIdx.y;
    if (ws->valid[row]) return;      // wave-uniform early exit
    f32x4* __restrict__ om = (f32x4*)(out_mask + (size_t)row * NN)
                             + blockIdx.x * QUOTA;
    const f32x4 z = {0.0f, 0.0f, 0.0f, 0.0f};
    const int t = threadIdx.x;
    #pragma unroll
    for (int i = 0; i < FULL_ITERS; ++i)
        __builtin_nontemporal_store(z, &om[t + i * TPB]);
    if (t < TAIL)
        __builtin_nontemporal_store(z, &om[FULL_ITERS * TPB + t]);
}

extern "C" void kernel_launch(void* const* d_in, const int* in_sizes, int n_in,
                              void* d_out, int out_size, void* d_ws, size_t ws_size,
                              hipStream_t stream) {
    const float* mask_logits = (const float*)d_in[0];   // [B,Q,N] f32
    const float* cls_logits  = (const float*)d_in[1];   // [B,Q,C] f32
    const int*   seg_pred    = (const int*)d_in[2];     // [B,N]   int
    const int*   fg_idxs     = (const int*)d_in[3];     // [B*N]   int

    float* out = (float*)d_out;
    Ws* ws = (Ws*)d_ws;

    // Output layout (flat, return order):
    //   [0, ROWS*NN)     proposal_masks
    //   [+ROWS)          scores
    //   [+ROWS)          valid
    //   [+ROWS)          cls_pred
    //   [+BB*NN)         global_ids
    float* out_mask = out;

    k0_argmax_zero<<<(ROWS + 255) / 256, 256, 0, stream>>>(cls_logits, ws);

    dim3 g1(BPR, ROWS);
    k1_select<<<g1, TPB, 0, stream>>>(mask_logits, seg_pred, out_mask, ws);

    const int gids_blocks = ((BB * NN) / 4 + 255) / 256;   // 196, covers ROWS too
    k2_finalize_gids<<<gids_blocks, 256, 0, stream>>>(fg_idxs, out, ws);

    k3_fixup<<<g1, TPB, 0, stream>>>(out_mask, ws);
}

// Round 2
// 201.064 us; speedup vs baseline: 1.0164x; 1.0164x over previous
//
#include <hip/hip_runtime.h>
#include <math.h>

// Problem constants (GeoFormer.generate_proposal, ScanNet config)
#define BB 4
#define QQ 128
#define NN 50000
#define CC 20
#define ROWS (BB * QQ)          // 512
#define NV4 (NN / 4)            // 12500 float4 per row
#define TPB 256
#define BPR 4                   // blocks per row (grid.x)
#define QUOTA (NV4 / BPR)       // 3125 f32x4 per block
#define FULL_ITERS 12           // 3125 = 12*256 + 53
#define TAIL 53
#define BATCH (4 * TPB)         // 1024 f32x4 per batch
#define THRESH_CNT 50
#define MIN_CLS 4

typedef float f32x4 __attribute__((ext_vector_type(4)));
typedef int   i32x4 __attribute__((ext_vector_type(4)));

// Workspace (re-initialized by k0 every call; harness poisons ws with 0xAA)
struct Ws {
    float sum[ROWS];
    int   cnt[ROWS];
    int   cls[ROWS];
    int   valid[ROWS];
};

// K0: per-(b,q) argmax over C=20 class logits (jnp.argmax tie-break = first
// max, i.e. strict '>' forward scan), and zero the accumulators.
__global__ void k0_argmax_zero(const float* __restrict__ cls_logits, Ws* ws) {
    int r = blockIdx.x * blockDim.x + threadIdx.x;
    if (r >= ROWS) return;
    const float* p = cls_logits + r * CC;
    float best = p[0];
    int bi = 0;
    #pragma unroll
    for (int c = 1; c < CC; ++c) {
        float v = p[c];
        if (v > best) { best = v; bi = c; }
    }
    ws->cls[r] = bi;
    ws->sum[r] = 0.0f;
    ws->cnt[r] = 0;
}

// Branchless select + sigmoid accumulate + PLAIN store (acks at L2 —
// NT stores retired at the memory controller and, via the in-order vmcnt
// queue, serialized every subsequent load-wait on HBM write latency).
__device__ __forceinline__ void proc4(const f32x4 vv, const i32x4 ss,
                                      const int cls, float& lsum, int& lcnt,
                                      f32x4* __restrict__ dst) {
    bool c0 = (vv.x > 0.0f) & (ss.x == cls);
    bool c1 = (vv.y > 0.0f) & (ss.y == cls);
    bool c2 = (vv.z > 0.0f) & (ss.z == cls);
    bool c3 = (vv.w > 0.0f) & (ss.w == cls);
    float g0 = 1.0f / (1.0f + __expf(-vv.x));
    float g1 = 1.0f / (1.0f + __expf(-vv.y));
    float g2 = 1.0f / (1.0f + __expf(-vv.z));
    float g3 = 1.0f / (1.0f + __expf(-vv.w));
    f32x4 o;
    o.x = c0 ? 1.0f : 0.0f;
    o.y = c1 ? 1.0f : 0.0f;
    o.z = c2 ? 1.0f : 0.0f;
    o.w = c3 ? 1.0f : 0.0f;
    lsum += (c0 ? g0 : 0.0f) + (c1 ? g1 : 0.0f)
          + (c2 ? g2 : 0.0f) + (c3 ? g3 : 0.0f);
    lcnt += (int)c0 + (int)c1 + (int)c2 + (int)c3;
    *dst = o;                       // plain global_store_dwordx4
}

// K1: main pass. grid = (BPR=4, ROWS). Each block owns a contiguous 3125
// f32x4 slice of one row. Explicit 2-deep register pipeline over 3 batches
// of 4 f32x4/thread; sched_barrier(0) fences keep the prefetch loads
// batched ahead of compute (R1: compiler sank them, VGPR fell to 32 and
// the pipeline vanished).
__global__ __launch_bounds__(256) void k1_select(
        const float* __restrict__ mask_logits,
        const int*   __restrict__ seg_pred,
        float* __restrict__ out_mask,
        Ws* __restrict__ ws) {
    const int row = blockIdx.y;          // 0..511  (b*Q + q)
    const int b   = row >> 7;            // row / Q
    const int cls = ws->cls[row];
    const int off = blockIdx.x * QUOTA;

    const f32x4* __restrict__ ml = (const f32x4*)(mask_logits + (size_t)row * NN) + off;
    const i32x4* __restrict__ sp = (const i32x4*)(seg_pred + b * NN) + off;
    f32x4* __restrict__ om = (f32x4*)(out_mask + (size_t)row * NN) + off;

    const int t = threadIdx.x;
    float lsum = 0.0f;
    int   lcnt = 0;

    f32x4 va[4]; i32x4 sa[4];
    f32x4 vb[4]; i32x4 sb[4];

    // batch 0 loads
    #pragma unroll
    for (int j = 0; j < 4; ++j) {
        va[j] = ml[t + j * TPB];
        sa[j] = sp[t + j * TPB];
    }
    __builtin_amdgcn_sched_barrier(0);
    // batch 1 loads (prefetch)
    #pragma unroll
    for (int j = 0; j < 4; ++j) {
        vb[j] = ml[BATCH + t + j * TPB];
        sb[j] = sp[BATCH + t + j * TPB];
    }
    __builtin_amdgcn_sched_barrier(0);
    // compute batch 0
    #pragma unroll
    for (int j = 0; j < 4; ++j)
        proc4(va[j], sa[j], cls, lsum, lcnt, &om[t + j * TPB]);
    __builtin_amdgcn_sched_barrier(0);
    // batch 2 loads (prefetch into va)
    #pragma unroll
    for (int j = 0; j < 4; ++j) {
        va[j] = ml[2 * BATCH + t + j * TPB];
        sa[j] = sp[2 * BATCH + t + j * TPB];
    }
    __builtin_amdgcn_sched_barrier(0);
    // compute batch 1
    #pragma unroll
    for (int j = 0; j < 4; ++j)
        proc4(vb[j], sb[j], cls, lsum, lcnt, &om[BATCH + t + j * TPB]);
    __builtin_amdgcn_sched_barrier(0);
    // compute batch 2
    #pragma unroll
    for (int j = 0; j < 4; ++j)
        proc4(va[j], sa[j], cls, lsum, lcnt, &om[2 * BATCH + t + j * TPB]);

    // ---- 53-lane tail (indices 3072..3124 of this block's quota) ----
    if (t < TAIL) {
        const int idx = FULL_ITERS * TPB + t;
        f32x4 vv = ml[idx];
        i32x4 ss = sp[idx];
        proc4(vv, ss, cls, lsum, lcnt, &om[idx]);
    }

    // ---- wave64 shuffle reduce + one atomic pair per block ----
    #pragma unroll
    for (int offr = 32; offr > 0; offr >>= 1) {
        lsum += __shfl_down(lsum, offr);
        lcnt += __shfl_down(lcnt, offr);
    }
    __shared__ float ssum[4];
    __shared__ int   scnt[4];
    const int wave = threadIdx.x >> 6;
    const int lane = threadIdx.x & 63;
    if (lane == 0) { ssum[wave] = lsum; scnt[wave] = lcnt; }
    __syncthreads();
    if (threadIdx.x == 0) {
        float ts = ssum[0] + ssum[1] + ssum[2] + ssum[3];
        int   tc = scnt[0] + scnt[1] + scnt[2] + scnt[3];
        atomicAdd(&ws->sum[row], ts);
        atomicAdd(&ws->cnt[row], tc);
    }
}

// K2: finalize per-row outputs (scores, valid, cls_pred) + global_ids copy.
__global__ void k2_finalize_gids(const int* __restrict__ fg,
                                 float* __restrict__ out,
                                 Ws* __restrict__ ws) {
    const int idx = blockIdx.x * blockDim.x + threadIdx.x;
    if (idx < ROWS) {
        int   cnt = ws->cnt[idx];
        int   cls = ws->cls[idx];
        float sum = ws->sum[idx];
        int valid = (cnt >= THRESH_CNT) && (cls >= MIN_CLS);
        ws->valid[idx] = valid;
        float* tail = out + (size_t)ROWS * NN;
        tail[idx]            = valid ? (sum / (float)max(cnt, 1)) : 0.0f;  // scores
        tail[ROWS + idx]     = valid ? 1.0f : 0.0f;                        // valid
        tail[2 * ROWS + idx] = (float)cls;                                 // cls_pred
    }
    const int nv4 = (BB * NN) / 4;   // 50000
    if (idx < nv4) {
        float* gids = out + (size_t)ROWS * NN + 3 * ROWS;
        i32x4 v = ((const i32x4*)fg)[idx];
        f32x4 o;
        o.x = (float)v.x; o.y = (float)v.y; o.z = (float)v.z; o.w = (float)v.w;
        ((f32x4*)gids)[idx] = o;
    }
}

// K3: zero the mask rows where !valid (expected ~20% of rows).
// grid = (BPR=4, ROWS); valid blocks exit after one uniform scalar load.
__global__ __launch_bounds__(256) void k3_fixup(
        float* __restrict__ out_mask, const Ws* __restrict__ ws) {
    const int row = blockIdx.y;
    if (ws->valid[row]) return;      // wave-uniform early exit
    f32x4* __restrict__ om = (f32x4*)(out_mask + (size_t)row * NN)
                             + blockIdx.x * QUOTA;
    const f32x4 z = {0.0f, 0.0f, 0.0f, 0.0f};
    const int t = threadIdx.x;
    #pragma unroll
    for (int i = 0; i < FULL_ITERS; ++i)
        om[t + i * TPB] = z;
    if (t < TAIL)
        om[FULL_ITERS * TPB + t] = z;
}

extern "C" void kernel_launch(void* const* d_in, const int* in_sizes, int n_in,
                              void* d_out, int out_size, void* d_ws, size_t ws_size,
                              hipStream_t stream) {
    const float* mask_logits = (const float*)d_in[0];   // [B,Q,N] f32
    const float* cls_logits  = (const float*)d_in[1];   // [B,Q,C] f32
    const int*   seg_pred    = (const int*)d_in[2];     // [B,N]   int
    const int*   fg_idxs     = (const int*)d_in[3];     // [B*N]   int

    float* out = (float*)d_out;
    Ws* ws = (Ws*)d_ws;

    // Output layout (flat, return order):
    //   [0, ROWS*NN)     proposal_masks
    //   [+ROWS)          scores
    //   [+ROWS)          valid
    //   [+ROWS)          cls_pred
    //   [+BB*NN)         global_ids
    float* out_mask = out;

    k0_argmax_zero<<<(ROWS + 255) / 256, 256, 0, stream>>>(cls_logits, ws);

    dim3 g1(BPR, ROWS);
    k1_select<<<g1, TPB, 0, stream>>>(mask_logits, seg_pred, out_mask, ws);

    const int gids_blocks = ((BB * NN) / 4 + 255) / 256;   // 196, covers ROWS too
    k2_finalize_gids<<<gids_blocks, 256, 0, stream>>>(fg_idxs, out, ws);

    k3_fixup<<<g1, TPB, 0, stream>>>(out_mask, ws);
}

// Round 3
// 200.300 us; speedup vs baseline: 1.0203x; 1.0038x over previous
//
#include <hip/hip_runtime.h>
#include <math.h>

// Problem constants (GeoFormer.generate_proposal, ScanNet config)
#define BB 4
#define QQ 128
#define NN 50000
#define CC 20
#define ROWS (BB * QQ)          // 512
#define NV4 (NN / 4)            // 12500 float4 per row
#define TPB 256
#define BPR 4                   // blocks per row (grid.x)
#define QUOTA (NV4 / BPR)       // 3125 f32x4 per block
#define FULL_ITERS 12           // 3125 = 12*256 + 53
#define TAIL 53
#define THRESH_CNT 50
#define MIN_CLS 4
#define NITER 13                // 12 full + 1 tail slot (bitmask layout)

typedef float f32x4 __attribute__((ext_vector_type(4)));
typedef int   i32x4 __attribute__((ext_vector_type(4)));
typedef unsigned long long u64;
typedef unsigned long long u64x2 __attribute__((ext_vector_type(2)));

// ---------------- new-path workspace ----------------
// Bitmask layout: per (row,bx) block, per iter (13), per wave (4): 4 u64
// planes b0..b3 where bit `lane` of plane j = sel for point
// ((bx*QUOTA + iter*TPB + wave*64 + lane)*4 + j). k1b inverts identically.
struct Ws2 {
    float psum[ROWS][BPR];      // per-block partial sigmoid sums
    int   pcnt[ROWS][BPR];      // per-block partial counts
    int   cls[ROWS];
    int   valid[ROWS];
    u64   bits[(size_t)ROWS * BPR * NITER * 16];   // 3.25 MiB
};

// ---------------- legacy-path workspace (fallback if ws too small) -------
struct Ws {
    float sum[ROWS];
    int   cnt[ROWS];
    int   cls[ROWS];
    int   valid[ROWS];
};

// ======================= NEW PATH =======================

// K1a: PURE-READ pass. grid = (BPR, ROWS). Reads ml+sp, computes per-point
// selection -> ballot bitmask into ws->bits, accumulates sigmoid sum/count
// -> non-atomic per-block partials. Computes row argmax locally (no k0).
__global__ __launch_bounds__(256) void k1a_reduce_bits(
        const float* __restrict__ mask_logits,
        const int*   __restrict__ seg_pred,
        const float* __restrict__ cls_logits,
        Ws2* __restrict__ ws) {
    const int row = blockIdx.y;
    const int b   = row >> 7;
    const int bx  = blockIdx.x;
    const int off = bx * QUOTA;

    // per-block argmax over C=20 (uniform addresses -> scalar loads; cheap)
    const float* cp = cls_logits + row * CC;
    float best = cp[0];
    int cls = 0;
    #pragma unroll
    for (int c = 1; c < CC; ++c) {
        float v = cp[c];
        if (v > best) { best = v; cls = c; }
    }

    const f32x4* __restrict__ ml = (const f32x4*)(mask_logits + (size_t)row * NN) + off;
    const i32x4* __restrict__ sp = (const i32x4*)(seg_pred + b * NN) + off;
    u64* __restrict__ wbits = ws->bits + (size_t)(row * BPR + bx) * NITER * 16;

    const int t = threadIdx.x;
    const int wave = t >> 6;
    const int lane = t & 63;

    float lsum = 0.0f;
    int   lcnt = 0;

    #pragma unroll 4
    for (int i = 0; i < FULL_ITERS; ++i) {
        f32x4 vv = ml[i * TPB + t];
        i32x4 ss = sp[i * TPB + t];
        bool c0 = (vv.x > 0.0f) & (ss.x == cls);
        bool c1 = (vv.y > 0.0f) & (ss.y == cls);
        bool c2 = (vv.z > 0.0f) & (ss.z == cls);
        bool c3 = (vv.w > 0.0f) & (ss.w == cls);
        float g0 = 1.0f / (1.0f + __expf(-vv.x));
        float g1 = 1.0f / (1.0f + __expf(-vv.y));
        float g2 = 1.0f / (1.0f + __expf(-vv.z));
        float g3 = 1.0f / (1.0f + __expf(-vv.w));
        lsum += (c0 ? g0 : 0.0f) + (c1 ? g1 : 0.0f)
              + (c2 ? g2 : 0.0f) + (c3 ? g3 : 0.0f);
        lcnt += (int)c0 + (int)c1 + (int)c2 + (int)c3;
        u64 b0 = __ballot(c0);
        u64 b1 = __ballot(c1);
        u64 b2 = __ballot(c2);
        u64 b3 = __ballot(c3);
        if (lane == 0) {
            u64x2* dst = (u64x2*)(wbits + (size_t)(i * 4 + wave) * 4);
            u64x2 q0; q0.x = b0; q0.y = b1;
            u64x2 q1; q1.x = b2; q1.y = b3;
            dst[0] = q0;
            dst[1] = q1;
        }
    }

    // tail: 53 threads (wave 0 only); ballot under divergence gives 0s for
    // inactive lanes, which is exactly what k1b's tail consumes.
    if (t < TAIL) {
        const int idx = FULL_ITERS * TPB + t;
        f32x4 vv = ml[idx];
        i32x4 ss = sp[idx];
        bool c0 = (vv.x > 0.0f) & (ss.x == cls);
        bool c1 = (vv.y > 0.0f) & (ss.y == cls);
        bool c2 = (vv.z > 0.0f) & (ss.z == cls);
        bool c3 = (vv.w > 0.0f) & (ss.w == cls);
        float g0 = 1.0f / (1.0f + __expf(-vv.x));
        float g1 = 1.0f / (1.0f + __expf(-vv.y));
        float g2 = 1.0f / (1.0f + __expf(-vv.z));
        float g3 = 1.0f / (1.0f + __expf(-vv.w));
        lsum += (c0 ? g0 : 0.0f) + (c1 ? g1 : 0.0f)
              + (c2 ? g2 : 0.0f) + (c3 ? g3 : 0.0f);
        lcnt += (int)c0 + (int)c1 + (int)c2 + (int)c3;
        u64 b0 = __ballot(c0);
        u64 b1 = __ballot(c1);
        u64 b2 = __ballot(c2);
        u64 b3 = __ballot(c3);
        if (lane == 0) {
            u64x2* dst = (u64x2*)(wbits + (size_t)(FULL_ITERS * 4 + 0) * 4);
            u64x2 q0; q0.x = b0; q0.y = b1;
            u64x2 q1; q1.x = b2; q1.y = b3;
            dst[0] = q0;
            dst[1] = q1;
        }
    }

    // wave64 shuffle reduce + one non-atomic partial per block
    #pragma unroll
    for (int offr = 32; offr > 0; offr >>= 1) {
        lsum += __shfl_down(lsum, offr);
        lcnt += __shfl_down(lcnt, offr);
    }
    __shared__ float ssum[4];
    __shared__ int   scnt[4];
    if (lane == 0) { ssum[wave] = lsum; scnt[wave] = lcnt; }
    __syncthreads();
    if (t == 0) {
        ws->psum[row][bx] = ssum[0] + ssum[1] + ssum[2] + ssum[3];
        ws->pcnt[row][bx] = scnt[0] + scnt[1] + scnt[2] + scnt[3];
        if (bx == 0) ws->cls[row] = cls;
    }
}

// K2new: finalize per-row outputs (scores, valid, cls_pred) + global_ids.
__global__ void k2_finalize_new(const int* __restrict__ fg,
                                float* __restrict__ out,
                                Ws2* __restrict__ ws) {
    const int idx = blockIdx.x * blockDim.x + threadIdx.x;
    if (idx < ROWS) {
        float sum = ws->psum[idx][0] + ws->psum[idx][1]
                  + ws->psum[idx][2] + ws->psum[idx][3];
        int   cnt = ws->pcnt[idx][0] + ws->pcnt[idx][1]
                  + ws->pcnt[idx][2] + ws->pcnt[idx][3];
        int   cls = ws->cls[idx];
        int valid = (cnt >= THRESH_CNT) && (cls >= MIN_CLS);
        ws->valid[idx] = valid;
        float* tail = out + (size_t)ROWS * NN;
        tail[idx]            = valid ? (sum / (float)max(cnt, 1)) : 0.0f;  // scores
        tail[ROWS + idx]     = valid ? 1.0f : 0.0f;                        // valid
        tail[2 * ROWS + idx] = (float)cls;                                 // cls_pred
    }
    const int nv4 = (BB * NN) / 4;   // 50000
    if (idx < nv4) {
        float* gids = out + (size_t)ROWS * NN + 3 * ROWS;
        i32x4 v = ((const i32x4*)fg)[idx];
        f32x4 o;
        o.x = (float)v.x; o.y = (float)v.y; o.z = (float)v.z; o.w = (float)v.w;
        ((f32x4*)gids)[idx] = o;
    }
}

// K1b: PURE-WRITE pass. grid = (BPR, ROWS). Reads wave-uniform 32B of
// bitmask per iter (L3-hot) + valid[row]; writes the full float mask.
// Invalid rows are written as zeros here -> k3 eliminated.
__global__ __launch_bounds__(256) void k1b_store(
        float* __restrict__ out_mask, const Ws2* __restrict__ ws) {
    const int row = blockIdx.y;
    const int bx  = blockIdx.x;
    const float validf = ws->valid[row] ? 1.0f : 0.0f;

    f32x4* __restrict__ om = (f32x4*)(out_mask + (size_t)row * NN) + bx * QUOTA;
    const u64* __restrict__ wbits =
        ws->bits + (size_t)(row * BPR + bx) * NITER * 16;

    const int t = threadIdx.x;
    const int wave = t >> 6;
    const int lane = t & 63;

    #pragma unroll 4
    for (int i = 0; i < FULL_ITERS; ++i) {
        const u64x2* pb = (const u64x2*)(wbits + (size_t)(i * 4 + wave) * 4);
        u64x2 q0 = pb[0];
        u64x2 q1 = pb[1];
        f32x4 o;
        o.x = ((q0.x >> lane) & 1ull) ? validf : 0.0f;
        o.y = ((q0.y >> lane) & 1ull) ? validf : 0.0f;
        o.z = ((q1.x >> lane) & 1ull) ? validf : 0.0f;
        o.w = ((q1.y >> lane) & 1ull) ? validf : 0.0f;
        om[i * TPB + t] = o;
    }
    if (t < TAIL) {
        const u64x2* pb = (const u64x2*)(wbits + (size_t)(FULL_ITERS * 4) * 4);
        u64x2 q0 = pb[0];
        u64x2 q1 = pb[1];
        f32x4 o;
        o.x = ((q0.x >> lane) & 1ull) ? validf : 0.0f;
        o.y = ((q0.y >> lane) & 1ull) ? validf : 0.0f;
        o.z = ((q1.x >> lane) & 1ull) ? validf : 0.0f;
        o.w = ((q1.y >> lane) & 1ull) ? validf : 0.0f;
        om[FULL_ITERS * TPB + t] = o;
    }
}

// ======================= LEGACY PATH (fallback if ws_size too small) =====

__global__ void k0_argmax_zero(const float* __restrict__ cls_logits, Ws* ws) {
    int r = blockIdx.x * blockDim.x + threadIdx.x;
    if (r >= ROWS) return;
    const float* p = cls_logits + r * CC;
    float best = p[0];
    int bi = 0;
    #pragma unroll
    for (int c = 1; c < CC; ++c) {
        float v = p[c];
        if (v > best) { best = v; bi = c; }
    }
    ws->cls[r] = bi;
    ws->sum[r] = 0.0f;
    ws->cnt[r] = 0;
}

__device__ __forceinline__ void proc4(const f32x4 vv, const i32x4 ss,
                                      const int cls, float& lsum, int& lcnt,
                                      f32x4* __restrict__ dst) {
    bool c0 = (vv.x > 0.0f) & (ss.x == cls);
    bool c1 = (vv.y > 0.0f) & (ss.y == cls);
    bool c2 = (vv.z > 0.0f) & (ss.z == cls);
    bool c3 = (vv.w > 0.0f) & (ss.w == cls);
    float g0 = 1.0f / (1.0f + __expf(-vv.x));
    float g1 = 1.0f / (1.0f + __expf(-vv.y));
    float g2 = 1.0f / (1.0f + __expf(-vv.z));
    float g3 = 1.0f / (1.0f + __expf(-vv.w));
    f32x4 o;
    o.x = c0 ? 1.0f : 0.0f;
    o.y = c1 ? 1.0f : 0.0f;
    o.z = c2 ? 1.0f : 0.0f;
    o.w = c3 ? 1.0f : 0.0f;
    lsum += (c0 ? g0 : 0.0f) + (c1 ? g1 : 0.0f)
          + (c2 ? g2 : 0.0f) + (c3 ? g3 : 0.0f);
    lcnt += (int)c0 + (int)c1 + (int)c2 + (int)c3;
    *dst = o;
}

__global__ __launch_bounds__(256) void k1_select(
        const float* __restrict__ mask_logits,
        const int*   __restrict__ seg_pred,
        float* __restrict__ out_mask,
        Ws* __restrict__ ws) {
    const int row = blockIdx.y;
    const int b   = row >> 7;
    const int cls = ws->cls[row];
    const int off = blockIdx.x * QUOTA;

    const f32x4* __restrict__ ml = (const f32x4*)(mask_logits + (size_t)row * NN) + off;
    const i32x4* __restrict__ sp = (const i32x4*)(seg_pred + b * NN) + off;
    f32x4* __restrict__ om = (f32x4*)(out_mask + (size_t)row * NN) + off;

    const int t = threadIdx.x;
    float lsum = 0.0f;
    int   lcnt = 0;

    #pragma unroll 4
    for (int i = 0; i < FULL_ITERS; ++i)
        proc4(ml[i * TPB + t], sp[i * TPB + t], cls, lsum, lcnt,
              &om[i * TPB + t]);
    if (t < TAIL) {
        const int idx = FULL_ITERS * TPB + t;
        proc4(ml[idx], sp[idx], cls, lsum, lcnt, &om[idx]);
    }

    #pragma unroll
    for (int offr = 32; offr > 0; offr >>= 1) {
        lsum += __shfl_down(lsum, offr);
        lcnt += __shfl_down(lcnt, offr);
    }
    __shared__ float ssum[4];
    __shared__ int   scnt[4];
    const int wave = threadIdx.x >> 6;
    const int lane = threadIdx.x & 63;
    if (lane == 0) { ssum[wave] = lsum; scnt[wave] = lcnt; }
    __syncthreads();
    if (threadIdx.x == 0) {
        atomicAdd(&ws->sum[row], ssum[0] + ssum[1] + ssum[2] + ssum[3]);
        atomicAdd(&ws->cnt[row], scnt[0] + scnt[1] + scnt[2] + scnt[3]);
    }
}

__global__ void k2_finalize_gids(const int* __restrict__ fg,
                                 float* __restrict__ out,
                                 Ws* __restrict__ ws) {
    const int idx = blockIdx.x * blockDim.x + threadIdx.x;
    if (idx < ROWS) {
        int   cnt = ws->cnt[idx];
        int   cls = ws->cls[idx];
        float sum = ws->sum[idx];
        int valid = (cnt >= THRESH_CNT) && (cls >= MIN_CLS);
        ws->valid[idx] = valid;
        float* tail = out + (size_t)ROWS * NN;
        tail[idx]            = valid ? (sum / (float)max(cnt, 1)) : 0.0f;
        tail[ROWS + idx]     = valid ? 1.0f : 0.0f;
        tail[2 * ROWS + idx] = (float)cls;
    }
    const int nv4 = (BB * NN) / 4;
    if (idx < nv4) {
        float* gids = out + (size_t)ROWS * NN + 3 * ROWS;
        i32x4 v = ((const i32x4*)fg)[idx];
        f32x4 o;
        o.x = (float)v.x; o.y = (float)v.y; o.z = (float)v.z; o.w = (float)v.w;
        ((f32x4*)gids)[idx] = o;
    }
}

__global__ __launch_bounds__(256) void k3_fixup(
        float* __restrict__ out_mask, const Ws* __restrict__ ws) {
    const int row = blockIdx.y;
    if (ws->valid[row]) return;
    f32x4* __restrict__ om = (f32x4*)(out_mask + (size_t)row * NN)
                             + blockIdx.x * QUOTA;
    const f32x4 z = {0.0f, 0.0f, 0.0f, 0.0f};
    const int t = threadIdx.x;
    #pragma unroll
    for (int i = 0; i < FULL_ITERS; ++i)
        om[t + i * TPB] = z;
    if (t < TAIL)
        om[FULL_ITERS * TPB + t] = z;
}

// ======================= launch =======================

extern "C" void kernel_launch(void* const* d_in, const int* in_sizes, int n_in,
                              void* d_out, int out_size, void* d_ws, size_t ws_size,
                              hipStream_t stream) {
    const float* mask_logits = (const float*)d_in[0];   // [B,Q,N] f32
    const float* cls_logits  = (const float*)d_in[1];   // [B,Q,C] f32
    const int*   seg_pred    = (const int*)d_in[2];     // [B,N]   int32 (JAX x64 off)
    const int*   fg_idxs     = (const int*)d_in[3];     // [B*N]   int32

    float* out = (float*)d_out;
    float* out_mask = out;

    // Output layout (flat, return order):
    //   [0, ROWS*NN)  proposal_masks | +ROWS scores | +ROWS valid
    //   +ROWS cls_pred | +BB*NN global_ids
    const int gids_blocks = ((BB * NN) / 4 + 255) / 256;   // 196, covers ROWS
    dim3 g1(BPR, ROWS);

    if (ws_size >= sizeof(Ws2)) {
        // Phase-separated path: pure-read reduce -> tiny finalize -> pure-write.
        Ws2* ws = (Ws2*)d_ws;
        k1a_reduce_bits<<<g1, TPB, 0, stream>>>(mask_logits, seg_pred,
                                                cls_logits, ws);
        k2_finalize_new<<<gids_blocks, 256, 0, stream>>>(fg_idxs, out, ws);
        k1b_store<<<g1, TPB, 0, stream>>>(out_mask, ws);
    } else {
        // Legacy fused path (R2): k0 -> k1 -> k2 -> k3.
        Ws* ws = (Ws*)d_ws;
        k0_argmax_zero<<<(ROWS + 255) / 256, 256, 0, stream>>>(cls_logits, ws);
        k1_select<<<g1, TPB, 0, stream>>>(mask_logits, seg_pred, out_mask, ws);
        k2_finalize_gids<<<gids_blocks, 256, 0, stream>>>(fg_idxs, out, ws);
        k3_fixup<<<g1, TPB, 0, stream>>>(out_mask, ws);
    }
}

// Round 4
// 190.275 us; speedup vs baseline: 1.0741x; 1.0527x over previous
//
#include <hip/hip_runtime.h>
#include <math.h>

// Problem constants (GeoFormer.generate_proposal, ScanNet config)
#define BB 4
#define QQ 128
#define NN 50000
#define CC 20
#define ROWS (BB * QQ)          // 512
#define NV4 (NN / 4)            // 12500 float4 per row
#define TPB1 1024               // one block per row, 16 waves
#define FULL1 12                // 12 * 1024 = 12288 f32x4
#define TAIL1 212               // 12500 - 12288
#define THRESH_CNT 50
#define MIN_CLS 4

typedef float f32x4 __attribute__((ext_vector_type(4)));
typedef int   i32x4 __attribute__((ext_vector_type(4)));
typedef unsigned long long u64;

// K1: ONE block per row (512 blocks x 1024 threads). Phase A: stream-read
// ml+sp, pack per-point selection into a register u64 (13 nibbles), reduce
// sigmoid sum/count block-locally -> valid known without any cross-block
// traffic (kills k0, k3, and the R3 bitmask round-trip). Phase B: unpack
// bits and NT-stream the float mask (pure write, no dependencies).
__global__ __launch_bounds__(1024) void k1_fused(
        const float* __restrict__ mask_logits,
        const int*   __restrict__ seg_pred,
        const float* __restrict__ cls_logits,
        float* __restrict__ out) {
    const int row = blockIdx.x;          // 0..511  (b*Q + q)
    const int b   = row >> 7;            // row / Q

    // Row-uniform argmax over C=20 (blockIdx-uniform addresses -> s_loads).
    // jnp.argmax tie-break = first max -> strict '>' forward scan.
    const float* cp = cls_logits + row * CC;
    float best = cp[0];
    int cls = 0;
    #pragma unroll
    for (int c = 1; c < CC; ++c) {
        float v = cp[c];
        if (v > best) { best = v; cls = c; }
    }

    const f32x4* __restrict__ ml = (const f32x4*)(mask_logits + (size_t)row * NN);
    const i32x4* __restrict__ sp = (const i32x4*)(seg_pred + b * NN);
    f32x4* __restrict__ om = (f32x4*)(out + (size_t)row * NN);

    const int t = threadIdx.x;
    u64   bits = 0;                      // 13 nibbles of selection bits
    float lsum = 0.0f;
    int   lcnt = 0;

    // ---------------- Phase A: pure read + reduce ----------------
    #pragma unroll 4
    for (int i = 0; i < FULL1; ++i) {
        f32x4 vv = ml[i * TPB1 + t];
        i32x4 ss = sp[i * TPB1 + t];
        // sigmoid(x) > 0.5  <=>  x > 0 ; branchless
        bool c0 = (vv.x > 0.0f) & (ss.x == cls);
        bool c1 = (vv.y > 0.0f) & (ss.y == cls);
        bool c2 = (vv.z > 0.0f) & (ss.z == cls);
        bool c3 = (vv.w > 0.0f) & (ss.w == cls);
        float g0 = 1.0f / (1.0f + __expf(-vv.x));
        float g1 = 1.0f / (1.0f + __expf(-vv.y));
        float g2 = 1.0f / (1.0f + __expf(-vv.z));
        float g3 = 1.0f / (1.0f + __expf(-vv.w));
        lsum += (c0 ? g0 : 0.0f) + (c1 ? g1 : 0.0f)
              + (c2 ? g2 : 0.0f) + (c3 ? g3 : 0.0f);
        lcnt += (int)c0 + (int)c1 + (int)c2 + (int)c3;
        u64 nib = (u64)c0 | ((u64)c1 << 1) | ((u64)c2 << 2) | ((u64)c3 << 3);
        bits |= nib << (4 * i);
    }
    if (t < TAIL1) {
        const int idx = FULL1 * TPB1 + t;
        f32x4 vv = ml[idx];
        i32x4 ss = sp[idx];
        bool c0 = (vv.x > 0.0f) & (ss.x == cls);
        bool c1 = (vv.y > 0.0f) & (ss.y == cls);
        bool c2 = (vv.z > 0.0f) & (ss.z == cls);
        bool c3 = (vv.w > 0.0f) & (ss.w == cls);
        float g0 = 1.0f / (1.0f + __expf(-vv.x));
        float g1 = 1.0f / (1.0f + __expf(-vv.y));
        float g2 = 1.0f / (1.0f + __expf(-vv.z));
        float g3 = 1.0f / (1.0f + __expf(-vv.w));
        lsum += (c0 ? g0 : 0.0f) + (c1 ? g1 : 0.0f)
              + (c2 ? g2 : 0.0f) + (c3 ? g3 : 0.0f);
        lcnt += (int)c0 + (int)c1 + (int)c2 + (int)c3;
        u64 nib = (u64)c0 | ((u64)c1 << 1) | ((u64)c2 << 2) | ((u64)c3 << 3);
        bits |= nib << (4 * FULL1);      // bits 48..51
    }

    // ---------------- block-local reduce -> valid ----------------
    #pragma unroll
    for (int offr = 32; offr > 0; offr >>= 1) {
        lsum += __shfl_down(lsum, offr);
        lcnt += __shfl_down(lcnt, offr);
    }
    __shared__ float ssum[16];
    __shared__ int   scnt[16];
    const int wave = t >> 6;
    const int lane = t & 63;
    if (lane == 0) { ssum[wave] = lsum; scnt[wave] = lcnt; }
    __syncthreads();
    float sum = 0.0f;
    int   cnt = 0;
    #pragma unroll
    for (int w = 0; w < 16; ++w) { sum += ssum[w]; cnt += scnt[w]; }
    const bool  valid  = (cnt >= THRESH_CNT) && (cls >= MIN_CLS);
    const float validf = valid ? 1.0f : 0.0f;

    if (t == 0) {
        float* tail = out + (size_t)ROWS * NN;
        tail[row]            = valid ? (sum / (float)max(cnt, 1)) : 0.0f;  // scores
        tail[ROWS + row]     = validf;                                     // valid
        tail[2 * ROWS + row] = (float)cls;                                 // cls_pred
    }

    // ---------------- Phase B: pure NT write from registers ----------------
    #pragma unroll 4
    for (int i = 0; i < FULL1; ++i) {
        u64 nib = bits >> (4 * i);
        f32x4 o;
        o.x = (nib & 1ull) ? validf : 0.0f;
        o.y = (nib & 2ull) ? validf : 0.0f;
        o.z = (nib & 4ull) ? validf : 0.0f;
        o.w = (nib & 8ull) ? validf : 0.0f;
        __builtin_nontemporal_store(o, &om[i * TPB1 + t]);
    }
    if (t < TAIL1) {
        u64 nib = bits >> (4 * FULL1);
        f32x4 o;
        o.x = (nib & 1ull) ? validf : 0.0f;
        o.y = (nib & 2ull) ? validf : 0.0f;
        o.z = (nib & 4ull) ? validf : 0.0f;
        o.w = (nib & 8ull) ? validf : 0.0f;
        __builtin_nontemporal_store(o, &om[FULL1 * TPB1 + t]);
    }
}

// K2: global_ids copy (int -> float), 50000 f32x4.
__global__ void k2_gids(const int* __restrict__ fg, float* __restrict__ out) {
    const int idx = blockIdx.x * blockDim.x + threadIdx.x;
    const int nv4 = (BB * NN) / 4;   // 50000
    if (idx < nv4) {
        float* gids = out + (size_t)ROWS * NN + 3 * ROWS;
        i32x4 v = ((const i32x4*)fg)[idx];
        f32x4 o;
        o.x = (float)v.x; o.y = (float)v.y; o.z = (float)v.z; o.w = (float)v.w;
        __builtin_nontemporal_store(o, &((f32x4*)gids)[idx]);
    }
}

extern "C" void kernel_launch(void* const* d_in, const int* in_sizes, int n_in,
                              void* d_out, int out_size, void* d_ws, size_t ws_size,
                              hipStream_t stream) {
    const float* mask_logits = (const float*)d_in[0];   // [B,Q,N] f32
    const float* cls_logits  = (const float*)d_in[1];   // [B,Q,C] f32
    const int*   seg_pred    = (const int*)d_in[2];     // [B,N]   int32
    const int*   fg_idxs     = (const int*)d_in[3];     // [B*N]   int32

    float* out = (float*)d_out;
    (void)d_ws; (void)ws_size;          // workspace no longer needed

    // Output layout (flat, return order):
    //   [0, ROWS*NN)  proposal_masks | +ROWS scores | +ROWS valid
    //   +ROWS cls_pred | +BB*NN global_ids
    k1_fused<<<ROWS, TPB1, 0, stream>>>(mask_logits, seg_pred, cls_logits, out);

    const int gids_blocks = ((BB * NN) / 4 + 255) / 256;   // 196
    k2_gids<<<gids_blocks, 256, 0, stream>>>(fg_idxs, out);
}

// Round 5
// 189.543 us; speedup vs baseline: 1.0782x; 1.0039x over previous
//
#include <hip/hip_runtime.h>
#include <math.h>

// Problem constants (GeoFormer.generate_proposal, ScanNet config)
#define BB 4
#define QQ 128
#define NN 50000
#define CC 20
#define ROWS (BB * QQ)          // 512
#define NV4 (NN / 4)            // 12500 float4 per row
#define TPB1 1024               // one block per row, 16 waves
#define FULL1 12                // 12 * 1024 = 12288 f32x4
#define TAIL1 212               // 12500 - 12288
#define THRESH_CNT 50
#define MIN_CLS 4
#define GIDS_V4 ((BB * NN) / 4)     // 50000 f32x4 of global_ids
#define GPB 98                      // ceil(50000/512) gid f32x4 per block

typedef float f32x4 __attribute__((ext_vector_type(4)));
typedef int   i32x4 __attribute__((ext_vector_type(4)));
typedef unsigned long long u64;

// Single-dispatch kernel. ONE block per row (512 x 1024). Phase A:
// stream-read ml+sp, pack per-point selection into a register u64 (13
// nibbles), block-reduce sigmoid sum/count -> valid locally (no workspace,
// no atomics, no cross-block traffic). Phase B: unpack bits, NT-stream the
// float mask (invalid rows written as zeros). Phase C: this block's 98-
// element slice of the global_ids int->float copy (folds old k2 dispatch).
//
// BW note (R0-R4): kernel BW is pinned at ~2.4 TB/s regardless of
// structure because the harness's 412 MB poison-fill drains dirty L3 to
// HBM concurrently with us (~3.9 TB/s hidden traffic; sum ~= 6.3 TB/s bus
// ceiling). Optimize dispatch count + byte count, not scheduling.
__global__ __launch_bounds__(1024) void k1_fused(
        const float* __restrict__ mask_logits,
        const int*   __restrict__ seg_pred,
        const float* __restrict__ cls_logits,
        const int*   __restrict__ fg,
        float* __restrict__ out) {
    const int row = blockIdx.x;          // 0..511  (b*Q + q)
    const int b   = row >> 7;            // row / Q

    // Row-uniform argmax over C=20 (blockIdx-uniform addresses -> s_loads).
    // jnp.argmax tie-break = first max -> strict '>' forward scan.
    const float* cp = cls_logits + row * CC;
    float best = cp[0];
    int cls = 0;
    #pragma unroll
    for (int c = 1; c < CC; ++c) {
        float v = cp[c];
        if (v > best) { best = v; cls = c; }
    }

    const f32x4* __restrict__ ml = (const f32x4*)(mask_logits + (size_t)row * NN);
    const i32x4* __restrict__ sp = (const i32x4*)(seg_pred + b * NN);
    f32x4* __restrict__ om = (f32x4*)(out + (size_t)row * NN);

    const int t = threadIdx.x;
    u64   bits = 0;                      // 13 nibbles of selection bits
    float lsum = 0.0f;
    int   lcnt = 0;

    // ---------------- Phase A: pure read + reduce ----------------
    #pragma unroll 4
    for (int i = 0; i < FULL1; ++i) {
        f32x4 vv = ml[i * TPB1 + t];
        i32x4 ss = sp[i * TPB1 + t];
        // sigmoid(x) > 0.5  <=>  x > 0 ; branchless
        bool c0 = (vv.x > 0.0f) & (ss.x == cls);
        bool c1 = (vv.y > 0.0f) & (ss.y == cls);
        bool c2 = (vv.z > 0.0f) & (ss.z == cls);
        bool c3 = (vv.w > 0.0f) & (ss.w == cls);
        float g0 = 1.0f / (1.0f + __expf(-vv.x));
        float g1 = 1.0f / (1.0f + __expf(-vv.y));
        float g2 = 1.0f / (1.0f + __expf(-vv.z));
        float g3 = 1.0f / (1.0f + __expf(-vv.w));
        lsum += (c0 ? g0 : 0.0f) + (c1 ? g1 : 0.0f)
              + (c2 ? g2 : 0.0f) + (c3 ? g3 : 0.0f);
        lcnt += (int)c0 + (int)c1 + (int)c2 + (int)c3;
        u64 nib = (u64)c0 | ((u64)c1 << 1) | ((u64)c2 << 2) | ((u64)c3 << 3);
        bits |= nib << (4 * i);
    }
    if (t < TAIL1) {
        const int idx = FULL1 * TPB1 + t;
        f32x4 vv = ml[idx];
        i32x4 ss = sp[idx];
        bool c0 = (vv.x > 0.0f) & (ss.x == cls);
        bool c1 = (vv.y > 0.0f) & (ss.y == cls);
        bool c2 = (vv.z > 0.0f) & (ss.z == cls);
        bool c3 = (vv.w > 0.0f) & (ss.w == cls);
        float g0 = 1.0f / (1.0f + __expf(-vv.x));
        float g1 = 1.0f / (1.0f + __expf(-vv.y));
        float g2 = 1.0f / (1.0f + __expf(-vv.z));
        float g3 = 1.0f / (1.0f + __expf(-vv.w));
        lsum += (c0 ? g0 : 0.0f) + (c1 ? g1 : 0.0f)
              + (c2 ? g2 : 0.0f) + (c3 ? g3 : 0.0f);
        lcnt += (int)c0 + (int)c1 + (int)c2 + (int)c3;
        u64 nib = (u64)c0 | ((u64)c1 << 1) | ((u64)c2 << 2) | ((u64)c3 << 3);
        bits |= nib << (4 * FULL1);      // bits 48..51
    }

    // ---------------- block-local reduce -> valid ----------------
    #pragma unroll
    for (int offr = 32; offr > 0; offr >>= 1) {
        lsum += __shfl_down(lsum, offr);
        lcnt += __shfl_down(lcnt, offr);
    }
    __shared__ float ssum[16];
    __shared__ int   scnt[16];
    const int wave = t >> 6;
    const int lane = t & 63;
    if (lane == 0) { ssum[wave] = lsum; scnt[wave] = lcnt; }
    __syncthreads();
    float sum = 0.0f;
    int   cnt = 0;
    #pragma unroll
    for (int w = 0; w < 16; ++w) { sum += ssum[w]; cnt += scnt[w]; }
    const bool  valid  = (cnt >= THRESH_CNT) && (cls >= MIN_CLS);
    const float validf = valid ? 1.0f : 0.0f;

    if (t == 0) {
        float* tail = out + (size_t)ROWS * NN;
        tail[row]            = valid ? (sum / (float)max(cnt, 1)) : 0.0f;  // scores
        tail[ROWS + row]     = validf;                                     // valid
        tail[2 * ROWS + row] = (float)cls;                                 // cls_pred
    }

    // ---------------- Phase B: pure NT write from registers ----------------
    #pragma unroll 4
    for (int i = 0; i < FULL1; ++i) {
        u64 nib = bits >> (4 * i);
        f32x4 o;
        o.x = (nib & 1ull) ? validf : 0.0f;
        o.y = (nib & 2ull) ? validf : 0.0f;
        o.z = (nib & 4ull) ? validf : 0.0f;
        o.w = (nib & 8ull) ? validf : 0.0f;
        __builtin_nontemporal_store(o, &om[i * TPB1 + t]);
    }
    if (t < TAIL1) {
        u64 nib = bits >> (4 * FULL1);
        f32x4 o;
        o.x = (nib & 1ull) ? validf : 0.0f;
        o.y = (nib & 2ull) ? validf : 0.0f;
        o.z = (nib & 4ull) ? validf : 0.0f;
        o.w = (nib & 8ull) ? validf : 0.0f;
        __builtin_nontemporal_store(o, &om[FULL1 * TPB1 + t]);
    }

    // ---------------- Phase C: this block's global_ids slice ----------------
    // Block `row` converts gid f32x4 indices [row*GPB, row*GPB+GPB) ∩ [0,GIDS_V4).
    if (t < GPB) {
        const int g = row * GPB + t;
        if (g < GIDS_V4) {
            float* gids = out + (size_t)ROWS * NN + 3 * ROWS;
            i32x4 v = ((const i32x4*)fg)[g];
            f32x4 o;
            o.x = (float)v.x; o.y = (float)v.y; o.z = (float)v.z; o.w = (float)v.w;
            __builtin_nontemporal_store(o, &((f32x4*)gids)[g]);
        }
    }
}

extern "C" void kernel_launch(void* const* d_in, const int* in_sizes, int n_in,
                              void* d_out, int out_size, void* d_ws, size_t ws_size,
                              hipStream_t stream) {
    const float* mask_logits = (const float*)d_in[0];   // [B,Q,N] f32
    const float* cls_logits  = (const float*)d_in[1];   // [B,Q,C] f32
    const int*   seg_pred    = (const int*)d_in[2];     // [B,N]   int32
    const int*   fg_idxs     = (const int*)d_in[3];     // [B*N]   int32

    float* out = (float*)d_out;
    (void)d_ws; (void)ws_size;          // workspace unused

    // Output layout (flat, return order):
    //   [0, ROWS*NN)  proposal_masks | +ROWS scores | +ROWS valid
    //   +ROWS cls_pred | +BB*NN global_ids
    k1_fused<<<ROWS, TPB1, 0, stream>>>(mask_logits, seg_pred, cls_logits,
                                        fg_idxs, out);
}